// Round 6
// baseline (354.753 us; speedup 1.0000x reference)
//
#include <hip/hip_runtime.h>
#include <stdint.h>

// YOLO loss: S=7, B=2, C=80. preds cell = 90 f32, target cell = 85 f32.
// Output: 4 f32 scalars (coords, obj, noobj, classes), summed over 401408 cells.
//
// v7: single fused nontemporal streaming pass.
//   Evidence (r5 post-mortem): four architectures (convoy-staged, DMA-staged,
//   wave-autonomous, pure-stream) all pin at 115-119us; FETCH varied 137->202MB
//   with ZERO time change -> not HBM-fetch-bound; invariant = 281MB unique
//   bytes / 116us = 2.42 TB/s L2-miss service rate. Theory test this round:
//   (A) L3 insert/evict throttle (footprint 281MB ~ L3 256MB) vs (B) fabric
//   directional ceiling (~3.15 TB/s read, if m13's 6.29 copy = R+W).
//   v7: __builtin_nontemporal_load on the preds stream (bypass cache insert)
//   + box loss merged into the stream via __shfl_down (cell's 10 box fields
//   live in 3 consecutive quads = 3 consecutive lanes) -> no second phase,
//   no uncoalesced re-read. (A) -> 60-85us; (B) -> ~unchanged -> roofline.

#define NPRED 90
#define NTGT  85
#define NCLS  80
#define TPB   256
#define NBLK  2048   // memory-bound: cap grid, grid-stride (G11)

typedef float vfloat4 __attribute__((ext_vector_type(4)));

__device__ __forceinline__ float sgnf(float x) {
    // matches jnp.sign: sign(0) == 0
    return (x > 0.0f) ? 1.0f : ((x < 0.0f) ? -1.0f : 0.0f);
}

__device__ __forceinline__ float iou_vs_target(
    float acx, float acy, float aw, float ah,
    float bx1, float by1, float bx2, float by2, float area_b)
{
    float ax1 = acx - aw * 0.5f, ay1 = acy - ah * 0.5f;
    float ax2 = acx + aw * 0.5f, ay2 = acy + ah * 0.5f;
    float iw = fmaxf(fminf(ax2, bx2) - fmaxf(ax1, bx1), 0.0f);
    float ih = fmaxf(fminf(ay2, by2) - fmaxf(ay1, by1), 0.0f);
    float inter = iw * ih;
    float area_a = (ax2 - ax1) * (ay2 - ay1);
    return inter / (area_a + area_b - inter);
}

// Full box loss for one cell given pb[]=p[80..89] and tb=targ row base.
__device__ __forceinline__ void box_loss(
    float pb0, float pb1, float pb2, float pb3, float pb4,
    float pb5, float pb6, float pb7, float pb8, float pb9,
    const float* __restrict__ tb,
    float& coords, float& objl, float& noobjl)
{
    float obj = tb[NCLS];
    float tcx = tb[81], tcy = tb[82], tw = tb[83], th = tb[84];
    float bx1 = tcx - tw * 0.5f, by1 = tcy - th * 0.5f;
    float bx2 = tcx + tw * 0.5f, by2 = tcy + th * 0.5f;
    float area_b = (bx2 - bx1) * (by2 - by1);

    // box1 = p[86..89], box2 = p[81..84]
    float iou1 = iou_vs_target(pb6, pb7, pb8, pb9, bx1, by1, bx2, by2, area_b);
    float iou2 = iou_vs_target(pb1, pb2, pb3, pb4, bx1, by1, bx2, by2, area_b);
    bool use2 = iou2 > iou1;  // argmax: tie -> box1

    float pcx = obj * (use2 ? pb1 : pb6);
    float pw  = obj * (use2 ? pb3 : pb8);
    float ph  = obj * (use2 ? pb4 : pb9);

    // center loss uses ONLY cx (ref's [..., :-3] on a 4-vector)
    float dc = pcx - tcx;
    float dw = sgnf(pw) * sqrtf(fabsf(pw) + 1e-6f) - sqrtf(tw);
    float dh = sgnf(ph) * sqrtf(fabsf(ph) + 1e-6f) - sqrtf(th);
    coords = fmaf(dc, dc, coords);
    coords = fmaf(dw, dw, coords);
    coords = fmaf(dh, dh, coords);

    float obj_pred = use2 ? pb0 : pb5;  // p[80] : p[85]
    float e1 = fmaf(obj, obj_pred, -obj);
    objl = fmaf(e1, e1, objl);
    float e2 = fmaf(1.0f - obj, obj_pred, -obj);
    noobjl = fmaf(e2, e2, noobjl);
}

// One quad of the preds stream. f = 4q. Even cells: classes at j=0..76,
// box quads j=80,84,88 (88 wraps 2 classes of next cell). Odd cells:
// classes j=2..78 (78 carries p80,p81 in z,w), box quads j=82,86.
// Owner lane (j==80 even / j==78 odd) assembles p[80..89] from its own quad
// + shfl_down(1,2) of the next two lanes' quads; lanes >=62 direct-load.
__device__ __forceinline__ void handle_quad(
    vfloat4 v, long long q, int lane,
    const float* __restrict__ preds, const float* __restrict__ targ,
    float& clsl, float& coords, float& objl, float& noobjl)
{
    // cross-lane pulls (wave-uniform execution; consecutive lanes hold
    // consecutive quads)
    float s1x = __shfl_down(v.x, 1), s1y = __shfl_down(v.y, 1);
    float s1z = __shfl_down(v.z, 1), s1w = __shfl_down(v.w, 1);
    float s2x = __shfl_down(v.x, 2), s2y = __shfl_down(v.y, 2);
    float s2z = __shfl_down(v.z, 2), s2w = __shfl_down(v.w, 2);

    unsigned f  = (unsigned)(4ll * q);
    unsigned cl = f / 90u;            // compiler magic-mul
    unsigned j  = f - cl * 90u;       // even
    const float* tb = targ + (size_t)cl * NTGT;

    if (j <= 76u) {
        float obj = tb[NCLS];
        float d0 = fmaf(v.x, obj, -tb[j]);
        float d1 = fmaf(v.y, obj, -tb[j + 1]);
        float d2 = fmaf(v.z, obj, -tb[j + 2]);
        float d3 = fmaf(v.w, obj, -tb[j + 3]);
        clsl = fmaf(d0, d0, clsl);
        clsl = fmaf(d1, d1, clsl);
        clsl = fmaf(d2, d2, clsl);
        clsl = fmaf(d3, d3, clsl);
    } else if (j == 78u) {
        float obj = tb[NCLS];
        float d0 = fmaf(v.x, obj, -tb[78]);
        float d1 = fmaf(v.y, obj, -tb[79]);
        clsl = fmaf(d0, d0, clsl);
        clsl = fmaf(d1, d1, clsl);
    } else if (j == 88u) {
        // z,w wrap to classes 0,1 of cl+1
        const float* t2 = tb + NTGT;
        float obj2 = t2[NCLS];
        float d0 = fmaf(v.z, obj2, -t2[0]);
        float d1 = fmaf(v.w, obj2, -t2[1]);
        clsl = fmaf(d0, d0, clsl);
        clsl = fmaf(d1, d1, clsl);
    }

    if (j == 80u) {          // even-cell box owner: v=p80..83, +1=p84..87, +2=p88,89
        if (lane < 62) {
            box_loss(v.x, v.y, v.z, v.w, s1x, s1y, s1z, s1w, s2x, s2y,
                     tb, coords, objl, noobjl);
        } else {             // helpers outside this wave's window: direct load
            const float* pB = preds + (size_t)cl * NPRED + NCLS;
            box_loss(pB[0], pB[1], pB[2], pB[3], pB[4],
                     pB[5], pB[6], pB[7], pB[8], pB[9],
                     tb, coords, objl, noobjl);
        }
    } else if (j == 78u) {   // odd-cell box owner: v.z,w=p80,81, +1=p82..85, +2=p86..89
        if (lane < 62) {
            box_loss(v.z, v.w, s1x, s1y, s1z, s1w, s2x, s2y, s2z, s2w,
                     tb, coords, objl, noobjl);
        } else {
            const float* pB = preds + (size_t)cl * NPRED + NCLS;
            box_loss(pB[0], pB[1], pB[2], pB[3], pB[4],
                     pB[5], pB[6], pB[7], pB[8], pB[9],
                     tb, coords, objl, noobjl);
        }
    }
}

__global__ __launch_bounds__(TPB, 2) void yolo_loss_kernel(
    const float* __restrict__ preds, const float* __restrict__ targ,
    float* __restrict__ part, float* __restrict__ out,
    int n_cells, int mode)
{
    __shared__ float red[4][4];

    float coords = 0.0f, objl = 0.0f, noobjl = 0.0f, clsl = 0.0f;

    const int tid  = threadIdx.x;
    const int lane = tid & 63;

    // n_quads is a multiple of 64 (n_cells even -> 90*n_cells % 4 == 0, and
    // 401408*90/4 = 9031680 = 64*141120) -> window bases are wave-uniform,
    // all 64 lanes always active at the shuffle points.
    const long long n_quads = ((long long)n_cells * NPRED) / 4;
    const long long tstride = (long long)gridDim.x * TPB;
    const vfloat4* pr4 = (const vfloat4*)preds;

    long long wb = (long long)blockIdx.x * TPB + (long long)(tid & ~63);

    // unroll 2: two nt quad-loads in flight per iteration
    for (; wb + tstride + 64 <= n_quads; wb += 2 * tstride) {
        vfloat4 va = __builtin_nontemporal_load(pr4 + wb + lane);
        vfloat4 vc = __builtin_nontemporal_load(pr4 + wb + tstride + lane);
        handle_quad(va, wb + lane,           lane, preds, targ,
                    clsl, coords, objl, noobjl);
        handle_quad(vc, wb + tstride + lane, lane, preds, targ,
                    clsl, coords, objl, noobjl);
    }
    for (; wb + 64 <= n_quads; wb += tstride) {
        vfloat4 va = __builtin_nontemporal_load(pr4 + wb + lane);
        handle_quad(va, wb + lane, lane, preds, targ,
                    clsl, coords, objl, noobjl);
    }

    // ---- wave reduce (64 lanes) ----
    #pragma unroll
    for (int off = 32; off > 0; off >>= 1) {
        coords += __shfl_down(coords, off);
        objl   += __shfl_down(objl, off);
        noobjl += __shfl_down(noobjl, off);
        clsl   += __shfl_down(clsl, off);
    }

    int wave = tid >> 6;
    if (lane == 0) {
        red[0][wave] = coords;
        red[1][wave] = objl;
        red[2][wave] = noobjl;
        red[3][wave] = clsl;
    }
    __syncthreads();
    if (tid == 0) {
        float c = red[0][0] + red[0][1] + red[0][2] + red[0][3];
        float o = red[1][0] + red[1][1] + red[1][2] + red[1][3];
        float n = red[2][0] + red[2][1] + red[2][2] + red[2][3];
        float k = red[3][0] + red[3][1] + red[3][2] + red[3][3];
        if (mode == 0) {
            // component-major partials: no contention, plain stores
            int nb = gridDim.x;
            part[0 * nb + blockIdx.x] = c;
            part[1 * nb + blockIdx.x] = o;
            part[2 * nb + blockIdx.x] = n;
            part[3 * nb + blockIdx.x] = k;
        } else {
            atomicAdd(&out[0], 5.0f * c);
            atomicAdd(&out[1], o);
            atomicAdd(&out[2], 0.5f * n);
            atomicAdd(&out[3], k);
        }
    }
}

// one block, 4 waves: wave w reduces component w over nblk partials
__global__ __launch_bounds__(256) void yolo_reduce_kernel(
    const float* __restrict__ part, float* __restrict__ out, int nblk)
{
    int w = threadIdx.x >> 6;
    int lane = threadIdx.x & 63;
    float s = 0.0f;
    for (int i = lane; i < nblk; i += 64) s += part[w * nblk + i];
    #pragma unroll
    for (int off = 32; off > 0; off >>= 1) s += __shfl_down(s, off);
    if (lane == 0) {
        float scale = (w == 0) ? 5.0f : (w == 2) ? 0.5f : 1.0f;
        out[w] = s * scale;  // plain store overwrites poison
    }
}

extern "C" void kernel_launch(void* const* d_in, const int* in_sizes, int n_in,
                              void* d_out, int out_size, void* d_ws, size_t ws_size,
                              hipStream_t stream) {
    const float* preds = (const float*)d_in[0];
    const float* targ  = (const float*)d_in[1];
    float* out = (float*)d_out;

    int n_cells = in_sizes[0] / NPRED;  // 8192*7*7 = 401408

    bool use_ws = ws_size >= (size_t)(4 * NBLK) * sizeof(float);

    if (use_ws) {
        float* part = (float*)d_ws;
        hipLaunchKernelGGL(yolo_loss_kernel, dim3(NBLK), dim3(TPB), 0, stream,
                           preds, targ, part, out, n_cells, 0);
        hipLaunchKernelGGL(yolo_reduce_kernel, dim3(1), dim3(256), 0, stream,
                           part, out, NBLK);
        if (out_size > 4) {
            hipMemsetAsync(out + 4, 0, (size_t)(out_size - 4) * sizeof(float), stream);
        }
    } else {
        // fallback: contended-atomic path (d_out poisoned -> zero first)
        hipMemsetAsync(d_out, 0, (size_t)out_size * sizeof(float), stream);
        hipLaunchKernelGGL(yolo_loss_kernel, dim3(NBLK), dim3(TPB), 0, stream,
                           preds, targ, (float*)nullptr, out, n_cells, 1);
    }
}

// Round 7
// 300.620 us; speedup vs baseline: 1.1801x; 1.1801x over previous
//
#include <hip/hip_runtime.h>

// YOLO loss: S=7, B=2, C=80. preds cell = 90 f32, target cell = 85 f32.
// Output: 4 f32 scalars (coords, obj, noobj, classes), summed over 401408 cells.
//
// FINAL (revert to v3, the best harness-verified variant: 297.5us total,
// 115.0us dispatch).
//
// ROOFLINE EVIDENCE (rounds 1-6): five architectures — per-thread AoS (v1),
// block-convoy reg-staging (v3), global_load_lds DMA pipeline (v4),
// wave-autonomous counted-vmcnt (v5), pure coalesced stream (v6), fused
// shuffle stream (v7) — sweep occupancy 26-85%, VALUBusy 3-56%, FETCH
// 137-255MB, and the minimum time pins at 115-116us in four independent
// designs = 281 MB unique bytes / 2.42 TB/s. That rate matches the chip's
// measured per-direction stream rate for compute kernels (m146 RMSNorm
// 4.89 TB/s R+W -> 2.45 TB/s/dir; m13 copy 6.29 TB/s R+W). 281 MB / 2.45
// TB/s = 114.7us floor; we are within ~1%. Every input byte is required;
// no further reduction is possible at fp32.
//
// Structure: 64-cell chunks; targ slab staged to LDS via coalesced float4;
// preds slab streamed through registers (classes loss elementwise, box
// fields scattered to padded LDS); one wave finishes IoU/coords/obj/noobj.
// Block partials go to d_ws via plain stores (NO contended atomics — r1
// showed 13-23ns per same-line RMW dominated: WRITE_SIZE scaled 4x with
// atomic count); a 1-block kernel reduces 4x1536 partials.

#define NPRED 90
#define NTGT  85
#define NCLS  80
#define CHUNK 64
#define TPB   256
#define PBS   11   // pbox leading-dim pad (odd -> conflict-free lane stride)
#define NBLK  1536 // 6 blocks/CU * 256 CUs (LDS-bound occupancy)

#define NT4 (CHUNK * NTGT / 4)   // 1360 float4 per targ slab
#define NP4 (CHUNK * NPRED / 4)  // 1440 float4 per preds slab

__device__ __forceinline__ float sgnf(float x) {
    // matches jnp.sign: sign(0) == 0
    return (x > 0.0f) ? 1.0f : ((x < 0.0f) ? -1.0f : 0.0f);
}

__device__ __forceinline__ float iou_vs_target(
    float acx, float acy, float aw, float ah,
    float bx1, float by1, float bx2, float by2, float area_b)
{
    float ax1 = acx - aw * 0.5f, ay1 = acy - ah * 0.5f;
    float ax2 = acx + aw * 0.5f, ay2 = acy + ah * 0.5f;
    float iw = fmaxf(fminf(ax2, bx2) - fmaxf(ax1, bx1), 0.0f);
    float ih = fmaxf(fminf(ay2, by2) - fmaxf(ay1, by1), 0.0f);
    float inter = iw * ih;
    float area_a = (ax2 - ax1) * (ay2 - ay1);
    return inter / (area_a + area_b - inter);
}

__device__ __forceinline__ void proc_elem(float v, int cl, int j, float obj,
    const float* __restrict__ t_lds, float* __restrict__ pbox, float& clsl)
{
    if (j < NCLS) {
        float tv = t_lds[cl * NTGT + j];
        float d = fmaf(v, obj, -tv);
        clsl = fmaf(d, d, clsl);
    } else {
        pbox[cl * PBS + (j - NCLS)] = v;
    }
}

__device__ __forceinline__ void proc_quad(float4 v, int q,
    const float* __restrict__ t_lds, float* __restrict__ pbox, float& clsl)
{
    int f  = 4 * q;            // flat element index within slab, even
    int cl = f / NPRED;        // magic-mul
    int j  = f - cl * NPRED;   // even, <= 88
    if (j != 88) {
        // all 4 elements in cell cl
        float obj = t_lds[cl * NTGT + NCLS];   // broadcast across same-cl lanes
        proc_elem(v.x, cl, j,     obj, t_lds, pbox, clsl);
        proc_elem(v.y, cl, j + 1, obj, t_lds, pbox, clsl);
        proc_elem(v.z, cl, j + 2, obj, t_lds, pbox, clsl);
        proc_elem(v.w, cl, j + 3, obj, t_lds, pbox, clsl);
    } else {
        // j=88,89 are box fields of cl; wrap to classes 0,1 of cl+1
        pbox[cl * PBS + 8] = v.x;
        pbox[cl * PBS + 9] = v.y;
        float obj2 = t_lds[(cl + 1) * NTGT + NCLS];
        proc_elem(v.z, cl + 1, 0, obj2, t_lds, pbox, clsl);
        proc_elem(v.w, cl + 1, 1, obj2, t_lds, pbox, clsl);
    }
}

__global__ __launch_bounds__(TPB) void yolo_loss_kernel(
    const float* __restrict__ preds, const float* __restrict__ targ,
    float* __restrict__ part, float* __restrict__ out,
    int n_cells, int mode)
{
    __shared__ __align__(16) float t_lds[CHUNK * NTGT];  // 21760 B
    __shared__ float pbox[CHUNK * PBS];                  // 2816 B
    __shared__ float red[4][4];

    float coords = 0.0f, objl = 0.0f, noobjl = 0.0f, clsl = 0.0f;

    const int tid = threadIdx.x;
    const int n_chunks = n_cells / CHUNK;

    for (int ch = blockIdx.x; ch < n_chunks; ch += gridDim.x) {
        // slab bases: ch*21760B and ch*23040B -> both 16B aligned
        const float4* tg4 = (const float4*)(targ  + (size_t)ch * (CHUNK * NTGT));
        const float4* pr4 = (const float4*)(preds + (size_t)ch * (CHUNK * NPRED));

        // ---- issue ALL global loads up front (one latency exposure) ----
        float4 t0 = tg4[tid];
        float4 t1 = tg4[tid + 256];
        float4 t2 = tg4[tid + 512];
        float4 t3 = tg4[tid + 768];
        float4 t4 = tg4[tid + 1024];
        const bool ht = tid < (NT4 - 1280);  // 80
        float4 t5 = make_float4(0.f, 0.f, 0.f, 0.f);
        if (ht) t5 = tg4[tid + 1280];

        float4 p0 = pr4[tid];
        float4 p1 = pr4[tid + 256];
        float4 p2 = pr4[tid + 512];
        float4 p3 = pr4[tid + 768];
        float4 p4 = pr4[tid + 1024];
        const bool hp = tid < (NP4 - 1280);  // 160
        float4 p5 = make_float4(0.f, 0.f, 0.f, 0.f);
        if (hp) p5 = pr4[tid + 1280];

        __syncthreads();  // previous iteration's box phase done reading LDS

        float4* tl4 = (float4*)t_lds;
        tl4[tid]        = t0;
        tl4[tid + 256]  = t1;
        tl4[tid + 512]  = t2;
        tl4[tid + 768]  = t3;
        tl4[tid + 1024] = t4;
        if (ht) tl4[tid + 1280] = t5;

        __syncthreads();  // t_lds ready

        // ---- classes loss + scatter box preds to LDS ----
        proc_quad(p0, tid,        t_lds, pbox, clsl);
        proc_quad(p1, tid + 256,  t_lds, pbox, clsl);
        proc_quad(p2, tid + 512,  t_lds, pbox, clsl);
        proc_quad(p3, tid + 768,  t_lds, pbox, clsl);
        proc_quad(p4, tid + 1024, t_lds, pbox, clsl);
        if (hp) proc_quad(p5, tid + 1280, t_lds, pbox, clsl);

        __syncthreads();  // pbox ready

        // ---- box losses: one wave, one lane per cell ----
        if (tid < CHUNK) {
            const float* pb = &pbox[tid * PBS];          // p[80..89]
            const float* tc = &t_lds[tid * NTGT + NCLS]; // t[80..84]
            float obj = tc[0];
            float tcx = tc[1], tcy = tc[2], tw = tc[3], th = tc[4];
            float bx1 = tcx - tw * 0.5f, by1 = tcy - th * 0.5f;
            float bx2 = tcx + tw * 0.5f, by2 = tcy + th * 0.5f;
            float area_b = (bx2 - bx1) * (by2 - by1);

            // box1 = p[86..89], box2 = p[81..84]
            float iou1 = iou_vs_target(pb[6], pb[7], pb[8], pb[9],
                                       bx1, by1, bx2, by2, area_b);
            float iou2 = iou_vs_target(pb[1], pb[2], pb[3], pb[4],
                                       bx1, by1, bx2, by2, area_b);
            bool use2 = iou2 > iou1;  // argmax: tie -> box1

            float pcx = obj * (use2 ? pb[1] : pb[6]);
            float pw  = obj * (use2 ? pb[3] : pb[8]);
            float ph  = obj * (use2 ? pb[4] : pb[9]);

            // center loss uses ONLY cx (ref's [..., :-3] on a 4-vector)
            float dc = pcx - tcx;
            float dw = sgnf(pw) * sqrtf(fabsf(pw) + 1e-6f) - sqrtf(tw);
            float dh = sgnf(ph) * sqrtf(fabsf(ph) + 1e-6f) - sqrtf(th);
            coords = fmaf(dc, dc, coords);
            coords = fmaf(dw, dw, coords);
            coords = fmaf(dh, dh, coords);

            float obj_pred = use2 ? pb[0] : pb[5];  // p[80] : p[85]
            float e1 = fmaf(obj, obj_pred, -obj);
            objl = fmaf(e1, e1, objl);
            float e2 = fmaf(1.0f - obj, obj_pred, -obj);
            noobjl = fmaf(e2, e2, noobjl);
        }
        // next iteration's first __syncthreads() guards LDS reuse
    }

    // ---- remainder cells (none when n_cells % 64 == 0): scalar fallback ----
    for (int cell = n_chunks * CHUNK + (int)(blockIdx.x * TPB + tid);
         cell < n_cells; cell += gridDim.x * TPB) {
        const float* p = preds + (size_t)cell * NPRED;
        const float* t = targ  + (size_t)cell * NTGT;
        float obj = t[NCLS];
        float cls = 0.0f;
        for (int k = 0; k < NCLS; ++k) {
            float d = fmaf(p[k], obj, -t[k]);
            cls = fmaf(d, d, cls);
        }
        clsl += cls;
        float tcx = t[81], tcy = t[82], tw = t[83], th = t[84];
        float bx1 = tcx - tw * 0.5f, by1 = tcy - th * 0.5f;
        float bx2 = tcx + tw * 0.5f, by2 = tcy + th * 0.5f;
        float area_b = (bx2 - bx1) * (by2 - by1);
        float iou1 = iou_vs_target(p[86], p[87], p[88], p[89],
                                   bx1, by1, bx2, by2, area_b);
        float iou2 = iou_vs_target(p[81], p[82], p[83], p[84],
                                   bx1, by1, bx2, by2, area_b);
        bool use2 = iou2 > iou1;
        float pcx = obj * (use2 ? p[81] : p[86]);
        float pw  = obj * (use2 ? p[83] : p[88]);
        float ph  = obj * (use2 ? p[84] : p[89]);
        float dc = pcx - tcx;
        float dw = sgnf(pw) * sqrtf(fabsf(pw) + 1e-6f) - sqrtf(tw);
        float dh = sgnf(ph) * sqrtf(fabsf(ph) + 1e-6f) - sqrtf(th);
        coords = fmaf(dc, dc, coords);
        coords = fmaf(dw, dw, coords);
        coords = fmaf(dh, dh, coords);
        float obj_pred = use2 ? p[80] : p[85];
        float e1 = fmaf(obj, obj_pred, -obj);
        objl = fmaf(e1, e1, objl);
        float e2 = fmaf(1.0f - obj, obj_pred, -obj);
        noobjl = fmaf(e2, e2, noobjl);
    }

    // ---- wave reduce (64 lanes) ----
    #pragma unroll
    for (int off = 32; off > 0; off >>= 1) {
        coords += __shfl_down(coords, off);
        objl   += __shfl_down(objl, off);
        noobjl += __shfl_down(noobjl, off);
        clsl   += __shfl_down(clsl, off);
    }

    int wave = threadIdx.x >> 6;
    int lane = threadIdx.x & 63;
    __syncthreads();
    if (lane == 0) {
        red[0][wave] = coords;
        red[1][wave] = objl;
        red[2][wave] = noobjl;
        red[3][wave] = clsl;
    }
    __syncthreads();
    if (threadIdx.x == 0) {
        float c = red[0][0] + red[0][1] + red[0][2] + red[0][3];
        float o = red[1][0] + red[1][1] + red[1][2] + red[1][3];
        float n = red[2][0] + red[2][1] + red[2][2] + red[2][3];
        float k = red[3][0] + red[3][1] + red[3][2] + red[3][3];
        if (mode == 0) {
            // component-major partials: no contention, plain stores
            int nb = gridDim.x;
            part[0 * nb + blockIdx.x] = c;
            part[1 * nb + blockIdx.x] = o;
            part[2 * nb + blockIdx.x] = n;
            part[3 * nb + blockIdx.x] = k;
        } else {
            atomicAdd(&out[0], 5.0f * c);
            atomicAdd(&out[1], o);
            atomicAdd(&out[2], 0.5f * n);
            atomicAdd(&out[3], k);
        }
    }
}

// one block, 4 waves: wave w reduces component w over nblk partials
__global__ __launch_bounds__(256) void yolo_reduce_kernel(
    const float* __restrict__ part, float* __restrict__ out, int nblk)
{
    int w = threadIdx.x >> 6;
    int lane = threadIdx.x & 63;
    float s = 0.0f;
    for (int i = lane; i < nblk; i += 64) s += part[w * nblk + i];
    #pragma unroll
    for (int off = 32; off > 0; off >>= 1) s += __shfl_down(s, off);
    if (lane == 0) {
        float scale = (w == 0) ? 5.0f : (w == 2) ? 0.5f : 1.0f;
        out[w] = s * scale;  // plain store overwrites poison
    }
}

extern "C" void kernel_launch(void* const* d_in, const int* in_sizes, int n_in,
                              void* d_out, int out_size, void* d_ws, size_t ws_size,
                              hipStream_t stream) {
    const float* preds = (const float*)d_in[0];
    const float* targ  = (const float*)d_in[1];
    float* out = (float*)d_out;

    int n_cells = in_sizes[0] / NPRED;  // 8192*7*7 = 401408

    bool use_ws = ws_size >= (size_t)(4 * NBLK) * sizeof(float);

    if (use_ws) {
        float* part = (float*)d_ws;
        hipLaunchKernelGGL(yolo_loss_kernel, dim3(NBLK), dim3(TPB), 0, stream,
                           preds, targ, part, out, n_cells, 0);
        hipLaunchKernelGGL(yolo_reduce_kernel, dim3(1), dim3(256), 0, stream,
                           part, out, NBLK);
        if (out_size > 4) {
            hipMemsetAsync(out + 4, 0, (size_t)(out_size - 4) * sizeof(float), stream);
        }
    } else {
        // fallback: contended-atomic path (d_out poisoned -> zero first)
        hipMemsetAsync(d_out, 0, (size_t)out_size * sizeof(float), stream);
        hipLaunchKernelGGL(yolo_loss_kernel, dim3(NBLK), dim3(TPB), 0, stream,
                           preds, targ, (float*)nullptr, out, n_cells, 1);
    }
}